// Round 13
// baseline (57.031 us; speedup 1.0000x reference)
//
#include <hip/hip_runtime.h>
#include <hip/hip_bf16.h>

// HMM forward via paired-step segmented matrix products (R13).
//
//   S_{t+1} S_t = diag(e_{t+1}) * G2[x_t],   G2[m] = A * diag(e_m) * A
//
// R13 = R10 (verified, 50.5us) + ONE structural change in hmm_seg:
//   each segment's pair chain is split into two INDEPENDENT half-chains
//   (Q = P_hi * P_lo), interleaved pair-by-pair in the same wave -> chain2's
//   MFMA/VALU fills chain1's dependency stalls (R11 ablation: chain exposure
//   = ~12us of seg's ~30us; no-chain floor 17.9us).
//   Combine: matrix stored in B-frag layout == its transpose in A-frag
//   layout, so P_hi is bounced through 8B/lane of LDS and re-read transposed
//   as the A operand of one extra MFMA: Q = P_hi * P_lo.
//   Renorm: chain1 per-column (factors out as Q column scaling); chain2
//   per-MATRIX (scalar ce2; per-column would mix into the contraction).
// Setup and comb verbatim R10.

#define NS    16
#define MOBS  64
#define SSH   5            // log2(nseg); nseg=32 -> L<=128 -> npair<=64
#define NSEG  32

typedef float f32x4 __attribute__((ext_vector_type(4)));
typedef short s16x4 __attribute__((ext_vector_type(4)));

static __device__ __forceinline__ int imin(int a, int b){ return a < b ? a : b; }

static __device__ __forceinline__ unsigned short f2bf(float f){
  return __bfloat16_as_ushort(__float2bfloat16(f));   // RNE (setup only)
}
static __device__ __forceinline__ float b2f(unsigned short u){
  unsigned bits = ((unsigned)u) << 16;
  return __builtin_bit_cast(float, bits);
}

static __device__ __forceinline__ s16x4 pack_bf16x4(f32x4 C){
  unsigned r0, r1;
  asm("v_cvt_pk_bf16_f32 %0, %1, %2" : "=v"(r0) : "v"(C.x), "v"(C.y));
  asm("v_cvt_pk_bf16_f32 %0, %1, %2" : "=v"(r1) : "v"(C.z), "v"(C.w));
  uint2 pu; pu.x = r0; pu.y = r1;
  return __builtin_bit_cast(s16x4, pu);
}

#if __has_builtin(__builtin_amdgcn_mfma_f32_16x16x16bf16_1k)
static __device__ __forceinline__ f32x4 mfma16(s16x4 a, s16x4 b, f32x4 c){
  return __builtin_amdgcn_mfma_f32_16x16x16bf16_1k(a, b, c, 0, 0, 0);
}
#else
static __device__ __forceinline__ f32x4 mfma16(s16x4 a, s16x4 b, f32x4 c){
  f32x4 d;
  asm volatile("v_mfma_f32_16x16x16_bf16 %0, %1, %2, %3"
               : "=&v"(d) : "v"(a), "v"(b), "v"(c));
  return d;
}
#endif

// ---------------- ws byte layout ----------------
//     0 : ET  f32 [64][16]                                  (4096 B)
//  4096 : pi  f32 [16]                                      (64 B)
//  8192 : g2  ushort:
//            [0,16384)      G2 slots 0..63 (MFMA A-frag order)
//            [16384,16640)  slot 64 = plain A frag (odd tails)
//            [16640,17664)  ET bf16 [64][16]
// 49152 : Q   ushort [B][NSEG][256]  (row-major [row][col])
//  then : CE  int    [B][NSEG][16]
// -------------------------------------------------

__global__ void hmm_setup(const float* __restrict__ tl, const float* __restrict__ el,
                          const float* __restrict__ pl, float* __restrict__ ws,
                          unsigned short* __restrict__ g2)
{
  int m = blockIdx.x, t = threadIdx.x;   // 65 blocks x 256 threads
  __shared__ float Al[256];
  __shared__ float ev[16];
  if (t < 16){
    float mx = -3.0e38f;
    for (int i = 0; i < 16; ++i) mx = fmaxf(mx, tl[i*NS + t]);
    float sm = 0.f;
    for (int i = 0; i < 16; ++i) sm += expf(tl[i*NS + t] - mx);
    float inv = 1.f / sm;
    for (int i = 0; i < 16; ++i) Al[i*16 + t] = expf(tl[i*NS + t] - mx) * inv;
  } else if (t < 32){
    int i = t - 16;
    if (m < 64){
      float mx = -3.0e38f;
      for (int mm = 0; mm < MOBS; ++mm) mx = fmaxf(mx, el[i*MOBS + mm]);
      float sm = 0.f;
      for (int mm = 0; mm < MOBS; ++mm) sm += expf(el[i*MOBS + mm] - mx);
      float v = expf(el[i*MOBS + m] - mx) / sm;
      ev[i] = v;
      ws[m*16 + i] = v;
      g2[16640 + m*16 + i] = f2bf(v);      // bf16 ET for seg LDS
    } else ev[i] = 1.f;
  } else if (t < 48 && m == 64){
    int i = t - 32;
    float mx = -3.0e38f;
    for (int k = 0; k < 16; ++k) mx = fmaxf(mx, pl[k]);
    float sm = 0.f;
    for (int k = 0; k < 16; ++k) sm += expf(pl[k] - mx);
    ws[1024 + i] = expf(pl[i] - mx) / sm;
  }
  __syncthreads();
  int l = t >> 2, e = t & 3;
  int i = l & 15, col = ((l >> 4) << 2) + e;
  float acc;
  if (m == 64){
    acc = Al[i*16 + col];
  } else {
    acc = 0.f;
    #pragma unroll
    for (int k = 0; k < 16; ++k) acc += Al[i*16 + k] * ev[k] * Al[k*16 + col];
  }
  g2[(m*64 + l)*4 + e] = f2bf(acc);
}

// 4 pairs of EACH chain, interleaved at pair granularity. Chain1 owns pairs
// [0,h), chain2 owns [h,npair). Memory clobber ends each pair region (pins
// prefetch >=4 pairs ahead; R10-verified safe). REN at p==3: chain1
// per-column, chain2 per-matrix.
template<bool MASK, bool REN>
static __device__ __forceinline__ void run_quad2(
    int p0, int h, int c2n,
    const unsigned short* g2l, const unsigned short* etl,
    int lane4, int g4, int xp,
    s16x4& P1, int& ce1,
    s16x4 (&gf1)[4], s16x4 (&ev1)[4], s16x4 (&g1n)[4], s16x4 (&e1n)[4],
    s16x4& P2, int& ce2,
    s16x4 (&gf2)[4], s16x4 (&ev2)[4], s16x4 (&g2n)[4], s16x4 (&e2n)[4])
{
  const f32x4 Z = {0.f, 0.f, 0.f, 0.f};
  #pragma unroll
  for (int p = 0; p < 4; ++p){
    {                                            // ---- chain 1, pair p0+p
      int v = __builtin_amdgcn_readlane(xp, (p0 + 4 + p) & 63);
      g1n[p] = *(const s16x4*)&g2l[(v & 63)*256 + lane4];
      e1n[p] = *(const s16x4*)&etl[((v >> 8) & 63)*16 + g4];

      f32x4 C = mfma16(gf1[p], P1, Z);
      C.x *= b2f((unsigned short)ev1[p].x);
      C.y *= b2f((unsigned short)ev1[p].y);
      C.z *= b2f((unsigned short)ev1[p].z);
      C.w *= b2f((unsigned short)ev1[p].w);

      bool commit = (!MASK) || (p0 + p < h);
      if (REN && p == 3){                        // per-column renorm
        float mm = fmaxf(fmaxf(C.x, C.y), fmaxf(C.z, C.w));
        mm = fmaxf(mm, __shfl_xor(mm, 16));
        mm = fmaxf(mm, __shfl_xor(mm, 32));
        int kk; (void)frexpf(mm, &kk);
        if (commit){
          C.x = ldexpf(C.x, -kk); C.y = ldexpf(C.y, -kk);
          C.z = ldexpf(C.z, -kk); C.w = ldexpf(C.w, -kk);
          ce1 += kk;
        }
      }
      if (commit) P1 = pack_bf16x4(C);
      asm volatile("" ::: "memory");
    }
    {                                            // ---- chain 2, pair h+p0+p
      int v = __builtin_amdgcn_readlane(xp, (h + p0 + 4 + p) & 63);
      g2n[p] = *(const s16x4*)&g2l[(v & 63)*256 + lane4];
      e2n[p] = *(const s16x4*)&etl[((v >> 8) & 63)*16 + g4];

      f32x4 D = mfma16(gf2[p], P2, Z);
      D.x *= b2f((unsigned short)ev2[p].x);
      D.y *= b2f((unsigned short)ev2[p].y);
      D.z *= b2f((unsigned short)ev2[p].z);
      D.w *= b2f((unsigned short)ev2[p].w);

      bool commit = (!MASK) || (p0 + p < c2n);
      if (REN && p == 3){                        // per-MATRIX renorm
        float mm = fmaxf(fmaxf(D.x, D.y), fmaxf(D.z, D.w));
        mm = fmaxf(mm, __shfl_xor(mm, 1));
        mm = fmaxf(mm, __shfl_xor(mm, 2));
        mm = fmaxf(mm, __shfl_xor(mm, 4));
        mm = fmaxf(mm, __shfl_xor(mm, 8));
        mm = fmaxf(mm, __shfl_xor(mm, 16));
        mm = fmaxf(mm, __shfl_xor(mm, 32));
        int kk; (void)frexpf(mm, &kk);
        if (commit){
          D.x = ldexpf(D.x, -kk); D.y = ldexpf(D.y, -kk);
          D.z = ldexpf(D.z, -kk); D.w = ldexpf(D.w, -kk);
          ce2 += kk;
        }
      }
      if (commit) P2 = pack_bf16x4(D);
      asm volatile("" ::: "memory");
    }
  }
}

__global__ __launch_bounds__(512, 1) void hmm_seg(
    const int* __restrict__ x, const int* __restrict__ Tl,
    const unsigned short* __restrict__ g2,
    unsigned short* __restrict__ Q, int* __restrict__ CE,
    int TMAX, int XN)
{
  int tid  = threadIdx.x;
  int lane = tid & 63;
  int wid  = __builtin_amdgcn_readfirstlane(tid >> 6);
  int g = lane >> 4, j = lane & 15;
  int lane4 = lane * 4, g4 = g * 4;

  int gseg = blockIdx.x * 8 + wid;
  int b = gseg >> SSH, s = gseg & (NSEG - 1);

  int steps = __builtin_amdgcn_readfirstlane(Tl[b]) - 1;
  int L  = (steps + NSEG - 1) >> SSH;
  int lo = s * L;
  int n  = imin(steps - lo, L);

  unsigned short* Qout = Q + (size_t)gseg * 256;
  int* ceout = CE + gseg * NS;

  int s_lo = (blockIdx.x & 3) * 8;
  if (s_lo * L >= steps){                   // whole block empty -> no staging
    if (g == 0) ceout[j] = 0;
    #pragma unroll
    for (int e = 0; e < 4; ++e){
      int k = 4*g + e;
      Qout[k*16 + j] = (k == j) ? (unsigned short)0x3F80 : (unsigned short)0;
    }
    return;
  }

  __shared__ unsigned short g2l[64*256];    // 32768 B
  __shared__ unsigned short etl[1024];      //  2048 B
  __shared__ unsigned short tb[2048];       //  4096 B bounce (256 ushorts/wave)
  {
    const uint4* s1 = (const uint4*)g2;
    const uint4* s2 = (const uint4*)(g2 + 16640);
    uint4* d1 = (uint4*)g2l;
    uint4* d2 = (uint4*)etl;
    for (int i = tid; i < 2048; i += 512) d1[i] = s1[i];
    if (tid < 128) d2[tid] = s2[tid];
  }
  __syncthreads();

  if (n <= 0){
    if (g == 0) ceout[j] = 0;
    #pragma unroll
    for (int e = 0; e < 4; ++e){
      int k = 4*g + e;
      Qout[k*16 + j] = (k == j) ? (unsigned short)0x3F80 : (unsigned short)0;
    }
    return;
  }

  int npair = n >> 1, odd = n & 1;
  int h   = npair >> 1;
  int c2n = npair - h;
  int xbase = b*TMAX + 1 + lo;

  int i0 = xbase + 2*lane;
  int xa = x[imin(i0,     XN - 1)] & 63;
  int xb = x[imin(i0 + 1, XN - 1)] & 63;
  int xp = xa | (xb << 8);

  s16x4 P1, P2;                             // identity (B-frag layout)
  P1.x = (4*g+0 == j) ? (short)0x3F80 : (short)0;
  P1.y = (4*g+1 == j) ? (short)0x3F80 : (short)0;
  P1.z = (4*g+2 == j) ? (short)0x3F80 : (short)0;
  P1.w = (4*g+3 == j) ? (short)0x3F80 : (short)0;
  P2 = P1;

  s16x4 gf1A[4], gf1B[4], ev1A[4], ev1B[4];
  s16x4 gf2A[4], gf2B[4], ev2A[4], ev2B[4];
  #pragma unroll
  for (int p = 0; p < 4; ++p){
    int v1 = __builtin_amdgcn_readlane(xp, p);
    gf1A[p] = *(const s16x4*)&g2l[(v1 & 63)*256 + lane4];
    ev1A[p] = *(const s16x4*)&etl[((v1 >> 8) & 63)*16 + g4];
    int v2 = __builtin_amdgcn_readlane(xp, (h + p) & 63);
    gf2A[p] = *(const s16x4*)&g2l[(v2 & 63)*256 + lane4];
    ev2A[p] = *(const s16x4*)&etl[((v2 >> 8) & 63)*16 + g4];
  }

  int ce1 = 0, ce2 = 0, p0 = 0;
  while (p0 + 8 <= h){
    run_quad2<false,false>(p0,   h, c2n, g2l, etl, lane4, g4, xp,
                           P1, ce1, gf1A, ev1A, gf1B, ev1B,
                           P2, ce2, gf2A, ev2A, gf2B, ev2B);
    run_quad2<false,true >(p0+4, h, c2n, g2l, etl, lane4, g4, xp,
                           P1, ce1, gf1B, ev1B, gf1A, ev1A,
                           P2, ce2, gf2B, ev2B, gf2A, ev2A);
    p0 += 8;
  }
  if (p0 < c2n){
    run_quad2<true,true>(p0, h, c2n, g2l, etl, lane4, g4, xp,
                         P1, ce1, gf1A, ev1A, gf1B, ev1B,
                         P2, ce2, gf2A, ev2A, gf2B, ev2B);
    if (p0 + 4 < c2n)
      run_quad2<true,true>(p0+4, h, c2n, g2l, etl, lane4, g4, xp,
                           P1, ce1, gf1B, ev1B, gf1A, ev1A,
                           P2, ce2, gf2B, ev2B, gf2A, ev2A);
  }

  // ---- combine: Q = P2 * P1 (P2 re-read transposed via LDS bounce) ----
  s16x4 A2;
  {
    unsigned short* twave = tb + wid*256;   // 256 ushorts = 512 B per wave
    ((uint2*)twave)[lane] = __builtin_bit_cast(uint2, P2);
    // halfword (l,e) of the write holds P2[k=4(l>>4)+e][j=l&15].
    // A-frag read: lane l, e needs P2[i=l&15][c=4(l>>4)+e] at ushort idx
    //   (l>>4)*16 + ((l&15)>>2)*64 + (l&3) + 4e.
    int base = (lane >> 4)*16 + ((lane & 15) >> 2)*64 + (lane & 3);
    unsigned u0 = twave[base +  0];
    unsigned u1 = twave[base +  4];
    unsigned u2 = twave[base +  8];
    unsigned u3 = twave[base + 12];
    uint2 au; au.x = u0 | (u1 << 16); au.y = u2 | (u3 << 16);
    A2 = __builtin_bit_cast(s16x4, au);
  }
  const f32x4 Z = {0.f,0.f,0.f,0.f};
  f32x4 C = mfma16(A2, P1, Z);
  {
    float mm = fmaxf(fmaxf(C.x, C.y), fmaxf(C.z, C.w));
    mm = fmaxf(mm, __shfl_xor(mm, 16));
    mm = fmaxf(mm, __shfl_xor(mm, 32));
    int kk; (void)frexpf(mm, &kk);
    C.x = ldexpf(C.x, -kk); C.y = ldexpf(C.y, -kk);
    C.z = ldexpf(C.z, -kk); C.w = ldexpf(C.w, -kk);
    ce1 += ce2 + kk;
  }
  s16x4 P = pack_bf16x4(C);

  if (odd){                                 // trailing single step: diag(e)*A
    int v = __builtin_amdgcn_readlane(xp, (n - 1) >> 1);
    int xm = v & 63;
    s16x4 af  = *(const s16x4*)&g2[16384 + lane4];
    s16x4 evo = *(const s16x4*)&etl[xm*16 + g4];
    f32x4 Co = mfma16(af, P, Z);
    Co.x *= b2f((unsigned short)evo.x); Co.y *= b2f((unsigned short)evo.y);
    Co.z *= b2f((unsigned short)evo.z); Co.w *= b2f((unsigned short)evo.w);
    P = pack_bf16x4(Co);
  }

  if (g == 0) ceout[j] = ce1;
  unsigned short pb[4] = {(unsigned short)P.x, (unsigned short)P.y,
                          (unsigned short)P.z, (unsigned short)P.w};
  #pragma unroll
  for (int e = 0; e < 4; ++e) Qout[(4*g + e)*16 + j] = pb[e];
}

__global__ __launch_bounds__(256) void hmm_comb(
    const int* __restrict__ x, const float* __restrict__ ws,
    const unsigned short* __restrict__ Q, const int* __restrict__ CE,
    float* __restrict__ out, int TMAX)
{
  int lane = threadIdx.x & 63;
  int w    = threadIdx.x >> 6;
  int b    = blockIdx.x * 4 + w;
  int k = lane & 15, r = lane >> 4;

  int x0 = x[b*TMAX];
  float u = ws[1024 + k] * ws[x0*16 + k];
  int ce_tot = 0;

  const unsigned short* qb = Q  + (size_t)b * NSEG * 256;
  const int*            cb = CE + b * NSEG * 16;

  s16x4 qq = *(const s16x4*)&qb[k*16 + 4*r];
  int4  cv = *(const int4*)&cb[4*r];

  for (int s = 0; s < NSEG; ++s){
    s16x4 qn; int4 cn;
    if (s + 1 < NSEG){
      qn = *(const s16x4*)&qb[(s+1)*256 + k*16 + 4*r];
      cn = *(const int4*)&cb[(s+1)*16 + 4*r];
    }
    int c0 = __builtin_amdgcn_readlane(cv.x, 0);
    float m0 = ldexpf(b2f((unsigned short)qq.x), cv.x - c0);
    float m1 = ldexpf(b2f((unsigned short)qq.y), cv.y - c0);
    float m2 = ldexpf(b2f((unsigned short)qq.z), cv.z - c0);
    float m3 = ldexpf(b2f((unsigned short)qq.w), cv.w - c0);

    float u0 = __shfl(u, 4*r + 0);
    float u1 = __shfl(u, 4*r + 1);
    float u2 = __shfl(u, 4*r + 2);
    float u3 = __shfl(u, 4*r + 3);
    float acc = m0*u0 + m1*u1 + m2*u2 + m3*u3;
    acc += __shfl_xor(acc, 16);
    acc += __shfl_xor(acc, 32);

    int ek; (void)frexpf(acc, &ek);
    int k0 = __builtin_amdgcn_readlane(ek, 0);
    u = ldexpf(acc, -k0);
    ce_tot += c0 + k0;

    qq = qn; cv = cn;
  }

  float sm = u;
  sm += __shfl_xor(sm, 1);
  sm += __shfl_xor(sm, 2);
  sm += __shfl_xor(sm, 4);
  sm += __shfl_xor(sm, 8);
  if (lane == 0) out[b] = ldexpf(sm, ce_tot);
}

extern "C" void kernel_launch(void* const* d_in, const int* in_sizes, int n_in,
                              void* d_out, int out_size, void* d_ws, size_t ws_size,
                              hipStream_t stream)
{
  (void)n_in; (void)out_size; (void)ws_size;
  const int*   x  = (const int*)  d_in[0];
  const int*   T  = (const int*)  d_in[1];
  const float* tl = (const float*)d_in[2];
  const float* el = (const float*)d_in[3];
  const float* pl = (const float*)d_in[4];
  int B    = in_sizes[1];
  int TMAX = in_sizes[0] / B;
  int XN   = B * TMAX;

  float* ws = (float*)d_ws;
  unsigned short* g2 = (unsigned short*)((char*)d_ws + 8192);
  unsigned short* Q  = (unsigned short*)((char*)d_ws + 49152);
  int* CE = (int*)((char*)d_ws + 49152 + (size_t)B * NSEG * 512);
  float* out = (float*)d_out;

  hipLaunchKernelGGL(hmm_setup, dim3(65),          dim3(256), 0, stream, tl, el, pl, ws, g2);
  hipLaunchKernelGGL(hmm_seg,   dim3(B*NSEG/8),    dim3(512), 0, stream, x, T, g2, Q, CE, TMAX, XN);
  hipLaunchKernelGGL(hmm_comb,  dim3(B/4),         dim3(256), 0, stream, x, ws, Q, CE, out, TMAX);
}